// Round 9
// baseline (5391.897 us; speedup 1.0000x reference)
//
#include <hip/hip_runtime.h>
#include <hip/hip_bf16.h>
#include <stdint.h>

#define BATCH  64
#define SEQ    1024
#define EMBED  128
#define HIDDEN 512
#define VOCAB  256

using bf16 = __hip_bfloat16;
typedef __attribute__((ext_vector_type(8))) short bf16x8;
typedef __attribute__((ext_vector_type(4))) float f32x4;

__device__ __forceinline__ float bfu(unsigned short u) {
    return __uint_as_float(((unsigned)u) << 16);
}

// ---------------- weight converts ----------------
__global__ void k_cvt(const float* __restrict__ in, bf16* __restrict__ out, int n) {
    int i = blockIdx.x * 256 + threadIdx.x;
    if (i < n) out[i] = __float2bfloat16(in[i]);
}

// W_xh [EMBED][HIDDEN] -> wxh_t [HIDDEN][EMBED] bf16
__global__ void k_txp_wxh(const float* __restrict__ in, bf16* __restrict__ out) {
    int idx = blockIdx.x * 256 + threadIdx.x;   // 65536
    int e = idx >> 9, j = idx & 511;
    out[j * EMBED + e] = __float2bfloat16(in[idx]);
}

// W_hh [K=512][N=512] -> wt [N=512][K=512] bf16
__global__ void k_txp_whh(const float* __restrict__ in, bf16* __restrict__ out) {
    int idx = blockIdx.x * 256 + threadIdx.x;   // 262144
    int k = idx >> 9, n = idx & 511;
    out[n * HIDDEN + k] = __float2bfloat16(in[idx]);
}

// ---------------- bf16 MFMA GEMM:  C[M][N] = A[M][K] * B'[N][K]^T + bias ----------------
// PERMUTE (phase-1 only): write C in the scan's per-thread-contiguous layout (R6 map).
template<bool GATHER, bool OUT_BF16, bool PERMUTE>
__global__ __launch_bounds__(256) void k_gemm(
    const bf16* __restrict__ A,       // [M][K]; if GATHER: embedding table [VOCAB][K]
    const int*  __restrict__ xtok,    // tokens [BATCH][SEQ] (GATHER only)
    const bf16* __restrict__ B,       // [N][K]
    const float* __restrict__ bias,   // [N]
    float* __restrict__ Cf,
    bf16*  __restrict__ Cb,
    int M, int N, int K)
{
    __shared__ bf16 As[64][72];
    __shared__ bf16 Bs[64][72];
    const int m0 = blockIdx.x * 64, n0 = blockIdx.y * 64;
    const int tid  = threadIdx.x;
    const int lane = tid & 63, wid = tid >> 6;
    const int wm = wid >> 1, wn = wid & 1;
    const int lrow = tid >> 3, lc8 = tid & 7;

    f32x4 acc[2][2] = {};

    for (int k0 = 0; k0 < K; k0 += 64) {
#pragma unroll
        for (int pass = 0; pass < 2; ++pass) {
            int row = pass * 32 + lrow;
            const bf16* asrc;
            if (GATHER) {
                int m = m0 + row;                 // m = t*BATCH + b
                int t = m >> 6, bb = m & 63;
                int tok = xtok[bb * SEQ + t];
                asrc = A + (size_t)tok * K + k0 + lc8 * 8;
            } else {
                asrc = A + (size_t)(m0 + row) * K + k0 + lc8 * 8;
            }
            *reinterpret_cast<uint4*>(&As[row][lc8 * 8]) = *reinterpret_cast<const uint4*>(asrc);
            *reinterpret_cast<uint4*>(&Bs[row][lc8 * 8]) =
                *reinterpret_cast<const uint4*>(B + (size_t)(n0 + row) * K + k0 + lc8 * 8);
        }
        __syncthreads();
#pragma unroll
        for (int kk = 0; kk < 2; ++kk) {
            bf16x8 af[2], bg[2];
#pragma unroll
            for (int mt = 0; mt < 2; ++mt)
                af[mt] = *reinterpret_cast<const bf16x8*>(
                    &As[wm * 32 + mt * 16 + (lane & 15)][kk * 32 + (lane >> 4) * 8]);
#pragma unroll
            for (int nt = 0; nt < 2; ++nt)
                bg[nt] = *reinterpret_cast<const bf16x8*>(
                    &Bs[wn * 32 + nt * 16 + (lane & 15)][kk * 32 + (lane >> 4) * 8]);
#pragma unroll
            for (int mt = 0; mt < 2; ++mt)
#pragma unroll
                for (int nt = 0; nt < 2; ++nt)
                    acc[mt][nt] = __builtin_amdgcn_mfma_f32_16x16x32_bf16(
                        af[mt], bg[nt], acc[mt][nt], 0, 0, 0);
        }
        __syncthreads();
    }
    if (PERMUTE) {
        const int t = m0 >> 6;
        const int wid_s = (n0 >> 5) + wn;
#pragma unroll
        for (int mt = 0; mt < 2; ++mt) {
            int blk = wm * 2 + mt;
            bf16 tmp[8];
#pragma unroll
            for (int nt = 0; nt < 2; ++nt) {
                int col = n0 + wn * 32 + nt * 16 + (lane & 15);
                float bv = bias[col];
#pragma unroll
                for (int r = 0; r < 4; ++r)
                    tmp[nt * 4 + r] = __float2bfloat16(acc[mt][nt][r] + bv);
            }
            size_t off = ((size_t)(t * 4 + blk) * 1024 +
                          wid_s * 64 + (lane >> 4) * 16 + (lane & 15)) * 8;
            *reinterpret_cast<uint4*>(Cb + off) = *reinterpret_cast<uint4*>(tmp);
        }
    } else {
#pragma unroll
        for (int mt = 0; mt < 2; ++mt) {
            int rbase = m0 + wm * 32 + mt * 16 + (lane >> 4) * 4;
#pragma unroll
            for (int nt = 0; nt < 2; ++nt) {
                int col = n0 + wn * 32 + nt * 16 + (lane & 15);
                float bv = bias[col];
#pragma unroll
                for (int r = 0; r < 4; ++r) {
                    float v = acc[mt][nt][r] + bv;
                    size_t off = (size_t)(rbase + r) * N + col;
                    if (OUT_BF16) Cb[off] = __float2bfloat16(v);
                    else          Cf[off] = v;
                }
            }
        }
    }
}

// ---------------- MFMA scan: 4 blocks x 16 rows, 16 waves x 32 N-cols ----------------
// ALL 16 W k-chunks AGPR-resident ("+a" pin; 512 KB of W per CU, zero per-step traffic).
// h in LDS, identity fragment order, 16B pad per 8 blocks (conflict-free R/W).
// 48 KB guard (write + post-barrier read into asm sink -> not DCE-able) pushes
// LDS to 84 KB so at most ONE block per CU (R7/R8 co-residency regression fix).
#define ROWS 16
#define CSTR 576      // chunk stride in bf16 (8 groups x 72)
#define GSTR 72       // group stride in bf16 (64 data + 8 pad)

__global__ __launch_bounds__(1024, 4) void k_scan_mfma(
    const bf16* __restrict__ xwp,   // permuted [SEQ*4][1024 tid][8]
    const bf16* __restrict__ wt,    // [HIDDEN n][HIDDEN k]
    const float* __restrict__ h0,   // [BATCH][HIDDEN]
    bf16* __restrict__ hh,          // [BATCH][SEQ][HIDDEN]
    float* __restrict__ hfin)       // [BATCH][HIDDEN]
{
    __shared__ bf16 hp[2][16 * CSTR];        // 2 x 18 KB
    __shared__ uint32_t guard[12288];        // 48 KB anti-co-residency pad

    const int tid  = threadIdx.x;
    const int lane = tid & 63, wid = tid >> 6;    // 16 waves
    const int b0   = blockIdx.x * ROWS;
    const int scol = wid * 32;                    // wave's 32-col slice
    const int lm   = lane & 15, lk = lane >> 4;

    guard[(tid * 37) & 12287] = tid;              // live write (read after barrier)

    // row-major slice <-> fragment addr (wave wid stores row wid, cols lane*8..+8)
    const int raddr = (lane >> 2) * CSTR + ((lane & 3) * 2 + (wid >> 3)) * GSTR + (wid & 7) * 8;
    // af read offset within hp[buf]: block = lane (identity, conflict-free)
    const int gofs  = (lane >> 3) * GSTR + (lane & 7) * 8;

    // ---- one-time: h0 -> hp[0] ----
    {
        const float* src = h0 + (size_t)(b0 + wid) * HIDDEN + lane * 8;
        bf16 tmp[8];
#pragma unroll
        for (int j = 0; j < 8; ++j) tmp[j] = __float2bfloat16(src[j]);
        *reinterpret_cast<uint4*>(&hp[0][raddr]) = *reinterpret_cast<uint4*>(&tmp[0]);
    }

    // ---- one-time: ALL W fragments -> AGPRs (128/wave), pinned vs remat ----
    bf16x8 breg[16][2];
#pragma unroll
    for (int c = 0; c < 16; ++c)
#pragma unroll
        for (int nt = 0; nt < 2; ++nt) {
            breg[c][nt] = *reinterpret_cast<const bf16x8*>(
                wt + (size_t)(scol + nt * 16 + lm) * HIDDEN + c * 32 + lk * 8);
            asm volatile("" : "+a"(breg[c][nt]));   // AGPR-resident, no remat
        }

    __syncthreads();

    {   // consume guard so it cannot be DCE'd (reads other threads' writes)
        uint32_t gs = guard[(tid + 512) & 12287];
        asm volatile("" :: "v"(gs));
    }

    int p = 0;
    for (int t = 0; t < SEQ; ++t) {
        // store h(t-1) -> hh (row-major reconstruct; hp[p] complete since barrier)
        if (t > 0) {
            uint4 v = *reinterpret_cast<const uint4*>(&hp[p][raddr]);
            *reinterpret_cast<uint4*>(
                hh + ((size_t)(b0 + wid) * SEQ + (t - 1)) * HIDDEN + lane * 8) = v;
        }

        // xw for this step: one uint4 (8 bf16) per thread
        ushort xe[8];
        *reinterpret_cast<uint4*>(&xe[0]) =
            *(reinterpret_cast<const uint4*>(xwp) +
              (size_t)(t * 4 + blockIdx.x) * 1024 + tid);

        f32x4 acc[2] = {};
#pragma unroll
        for (int kc = 0; kc < 16; ++kc) {
            bf16x8 af = *reinterpret_cast<const bf16x8*>(&hp[p][kc * CSTR + gofs]);
            acc[0] = __builtin_amdgcn_mfma_f32_16x16x32_bf16(af, breg[kc][0], acc[0], 0, 0, 0);
            acc[1] = __builtin_amdgcn_mfma_f32_16x16x32_bf16(af, breg[kc][1], acc[1], 0, 0, 0);
        }

        // epilogue: h_new -> hp[p^1], fragment order (conflict-free padded scatter)
        {
            bf16* hw = &hp[p ^ 1][wid * CSTR];
#pragma unroll
            for (int nt = 0; nt < 2; ++nt)
#pragma unroll
                for (int r = 0; r < 4; ++r) {
                    float pre = acc[nt][r] + bfu(xe[nt * 4 + r]);
                    float e2  = __expf(2.f * pre);
                    float rc  = __builtin_amdgcn_rcpf(e2 + 1.f);
                    float hn  = fmaf(-2.f, rc, 1.f);        // tanh(pre)
                    int blk = (nt * 2 + (lm >> 3)) * 16 + lk * 4 + r;
                    hw[(blk >> 3) * GSTR + (blk & 7) * 8 + (lm & 7)] = __float2bfloat16(hn);
                }
        }
        p ^= 1;
        __syncthreads();    // single barrier per step
    }

    // final: h(SEQ-1) -> hh and hfin (row-major reconstruct)
    {
        uint4 v = *reinterpret_cast<const uint4*>(&hp[p][raddr]);
        *reinterpret_cast<uint4*>(
            hh + ((size_t)(b0 + wid) * SEQ + (SEQ - 1)) * HIDDEN + lane * 8) = v;
        const ushort* u = reinterpret_cast<const ushort*>(&v);
        float* dst = hfin + (size_t)(b0 + wid) * HIDDEN + lane * 8;
#pragma unroll
        for (int j = 0; j < 8; ++j) dst[j] = bfu(u[j]);
    }
}

// ---------------- launch ----------------
extern "C" void kernel_launch(void* const* d_in, const int* in_sizes, int n_in,
                              void* d_out, int out_size, void* d_ws, size_t ws_size,
                              hipStream_t stream) {
    const int*   x    = (const int*)  d_in[0];
    const float* h0   = (const float*)d_in[1];
    const float* emb  = (const float*)d_in[2];
    const float* wxh  = (const float*)d_in[3];
    const float* whh  = (const float*)d_in[4];
    const float* bh   = (const float*)d_in[5];
    const float* whyw = (const float*)d_in[6];
    const float* whyb = (const float*)d_in[7];

    float* logits = (float*)d_out;                            // [BATCH][SEQ][VOCAB]
    float* hfin   = logits + (size_t)BATCH * SEQ * VOCAB;     // [BATCH][HIDDEN]

    char* p = (char*)d_ws;
    bf16* xwp    = (bf16*)p; p += (size_t)SEQ * BATCH * HIDDEN * 2;
    bf16* hh     = (bf16*)p; p += (size_t)BATCH * SEQ * HIDDEN * 2;
    bf16* wt     = (bf16*)p; p += (size_t)HIDDEN * HIDDEN * 2;
    bf16* wxh_t  = (bf16*)p; p += (size_t)HIDDEN * EMBED * 2;
    bf16* emb_bf = (bf16*)p; p += (size_t)VOCAB * EMBED * 2;
    bf16* why_bf = (bf16*)p; p += (size_t)VOCAB * HIDDEN * 2;

    k_txp_whh<<<(HIDDEN * HIDDEN + 255) / 256, 256, 0, stream>>>(whh, wt);
    k_cvt<<<(VOCAB * EMBED + 255) / 256, 256, 0, stream>>>(emb, emb_bf, VOCAB * EMBED);
    k_cvt<<<(VOCAB * HIDDEN + 255) / 256, 256, 0, stream>>>(whyw, why_bf, VOCAB * HIDDEN);
    k_txp_wxh<<<(EMBED * HIDDEN + 255) / 256, 256, 0, stream>>>(wxh, wxh_t);

    // phase 1: xwp = permute(emb[x] @ W_xh + b_h)
    k_gemm<true, true, true><<<dim3((SEQ * BATCH) / 64, HIDDEN / 64), 256, 0, stream>>>(
        emb_bf, x, wxh_t, bh, nullptr, xwp, SEQ * BATCH, HIDDEN, EMBED);

    // phase 2: the recurrence (4 blocks x 16 batch rows, 1024 threads)
    k_scan_mfma<<<BATCH / ROWS, 1024, 0, stream>>>(xwp, wt, h0, hh, hfin);

    // phase 3: logits = hh @ W_hy^T + b
    k_gemm<false, false, false><<<dim3((BATCH * SEQ) / 64, VOCAB / 64), 256, 0, stream>>>(
        hh, nullptr, why_bf, whyb, logits, nullptr, BATCH * SEQ, VOCAB, HIDDEN);
}

// Round 10
// 4000.838 us; speedup vs baseline: 1.3477x; 1.3477x over previous
//
#include <hip/hip_runtime.h>
#include <hip/hip_bf16.h>
#include <stdint.h>

#define BATCH  64
#define SEQ    1024
#define EMBED  128
#define HIDDEN 512
#define VOCAB  256

using bf16 = __hip_bfloat16;
typedef __attribute__((ext_vector_type(8))) short bf16x8;
typedef __attribute__((ext_vector_type(4))) float f32x4;

__device__ __forceinline__ float bfu(unsigned short u) {
    return __uint_as_float(((unsigned)u) << 16);
}

// ---------------- weight converts ----------------
__global__ void k_cvt(const float* __restrict__ in, bf16* __restrict__ out, int n) {
    int i = blockIdx.x * 256 + threadIdx.x;
    if (i < n) out[i] = __float2bfloat16(in[i]);
}

// W_xh [EMBED][HIDDEN] -> wxh_t [HIDDEN][EMBED] bf16
__global__ void k_txp_wxh(const float* __restrict__ in, bf16* __restrict__ out) {
    int idx = blockIdx.x * 256 + threadIdx.x;   // 65536
    int e = idx >> 9, j = idx & 511;
    out[j * EMBED + e] = __float2bfloat16(in[idx]);
}

// W_hh [K=512][N=512] -> wt [N=512][K=512] bf16
__global__ void k_txp_whh(const float* __restrict__ in, bf16* __restrict__ out) {
    int idx = blockIdx.x * 256 + threadIdx.x;   // 262144
    int k = idx >> 9, n = idx & 511;
    out[n * HIDDEN + k] = __float2bfloat16(in[idx]);
}

// ---------------- bf16 MFMA GEMM:  C[M][N] = A[M][K] * B'[N][K]^T + bias ----------------
// PERMUTE (phase-1 only, R5-style 512-thread layout): elem(row=t*64+b, col) ->
//   xwp[(t*4 + b>>4)*8192 + (col>>6)*1024 + lane*16 + ((col&63)>>4)*4 + (b&3)]
//   where lane = ((b&15)>>2)*16 + (col&15).
template<bool GATHER, bool OUT_BF16, bool PERMUTE>
__global__ __launch_bounds__(256) void k_gemm(
    const bf16* __restrict__ A,       // [M][K]; if GATHER: embedding table [VOCAB][K]
    const int*  __restrict__ xtok,    // tokens [BATCH][SEQ] (GATHER only)
    const bf16* __restrict__ B,       // [N][K]
    const float* __restrict__ bias,   // [N]
    float* __restrict__ Cf,
    bf16*  __restrict__ Cb,
    int M, int N, int K)
{
    __shared__ bf16 As[64][72];
    __shared__ bf16 Bs[64][72];
    const int m0 = blockIdx.x * 64, n0 = blockIdx.y * 64;
    const int tid  = threadIdx.x;
    const int lane = tid & 63, wid = tid >> 6;
    const int wm = wid >> 1, wn = wid & 1;
    const int lrow = tid >> 3, lc8 = tid & 7;

    f32x4 acc[2][2] = {};

    for (int k0 = 0; k0 < K; k0 += 64) {
#pragma unroll
        for (int pass = 0; pass < 2; ++pass) {
            int row = pass * 32 + lrow;
            const bf16* asrc;
            if (GATHER) {
                int m = m0 + row;                 // m = t*BATCH + b
                int t = m >> 6, bb = m & 63;
                int tok = xtok[bb * SEQ + t];
                asrc = A + (size_t)tok * K + k0 + lc8 * 8;
            } else {
                asrc = A + (size_t)(m0 + row) * K + k0 + lc8 * 8;
            }
            *reinterpret_cast<uint4*>(&As[row][lc8 * 8]) = *reinterpret_cast<const uint4*>(asrc);
            *reinterpret_cast<uint4*>(&Bs[row][lc8 * 8]) =
                *reinterpret_cast<const uint4*>(B + (size_t)(n0 + row) * K + k0 + lc8 * 8);
        }
        __syncthreads();
#pragma unroll
        for (int kk = 0; kk < 2; ++kk) {
            bf16x8 af[2], bg[2];
#pragma unroll
            for (int mt = 0; mt < 2; ++mt)
                af[mt] = *reinterpret_cast<const bf16x8*>(
                    &As[wm * 32 + mt * 16 + (lane & 15)][kk * 32 + (lane >> 4) * 8]);
#pragma unroll
            for (int nt = 0; nt < 2; ++nt)
                bg[nt] = *reinterpret_cast<const bf16x8*>(
                    &Bs[wn * 32 + nt * 16 + (lane & 15)][kk * 32 + (lane >> 4) * 8]);
#pragma unroll
            for (int mt = 0; mt < 2; ++mt)
#pragma unroll
                for (int nt = 0; nt < 2; ++nt)
                    acc[mt][nt] = __builtin_amdgcn_mfma_f32_16x16x32_bf16(
                        af[mt], bg[nt], acc[mt][nt], 0, 0, 0);
        }
        __syncthreads();
    }
    if (PERMUTE) {
        const int t = m0 >> 6, wid_s = n0 >> 6;
#pragma unroll
        for (int mt = 0; mt < 2; ++mt) {
            int blk = wm * 2 + mt;
            bf16 tmp[8];
#pragma unroll
            for (int nt = 0; nt < 2; ++nt) {
                int col = n0 + wn * 32 + nt * 16 + (lane & 15);
                float bv = bias[col];
#pragma unroll
                for (int r = 0; r < 4; ++r)
                    tmp[nt * 4 + r] = __float2bfloat16(acc[mt][nt][r] + bv);
            }
            size_t off = (((size_t)(t * 4 + blk) * 512) + wid_s * 64 + lane) * 16 + wn * 8;
            *reinterpret_cast<uint4*>(Cb + off) = *reinterpret_cast<uint4*>(tmp);
        }
    } else {
#pragma unroll
        for (int mt = 0; mt < 2; ++mt) {
            int rbase = m0 + wm * 32 + mt * 16 + (lane >> 4) * 4;
#pragma unroll
            for (int nt = 0; nt < 2; ++nt) {
                int col = n0 + wn * 32 + nt * 16 + (lane & 15);
                float bv = bias[col];
#pragma unroll
                for (int r = 0; r < 4; ++r) {
                    float v = acc[mt][nt][r] + bv;
                    size_t off = (size_t)(rbase + r) * N + col;
                    if (OUT_BF16) Cb[off] = __float2bfloat16(v);
                    else          Cf[off] = v;
                }
            }
        }
    }
}

// ---------------- MFMA scan: 4 blocks x 16 rows, 8 waves x 64 N-cols ----------------
// ALL 16 W k-chunks register-resident: breg[16][4] = 256 VGPR/wave ("+v" pin,
// launch_bounds(512,1) -> 512-reg budget). Zero per-step W traffic from any pipe.
// h in LDS, identity fragment order; CSTR=584 (chunk stride == 4 mod 32 dwords)
// makes af reads, epilogue writes AND row-major hh/h0 accesses all conflict-free.
//   addr(col c, row m) = (c>>5)*CSTR + ((((c&31)>>3)*2)+(m>>3))*GSTR + (m&7)*8 + (c&7)
#define ROWS 16
#define GSTR 72       // group stride in bf16 (64 data + 8 pad)
#define CSTR 584      // chunk stride in bf16 (8 groups x 72 + 8 pad -> 292 dw = 4 mod 32)

__global__ __launch_bounds__(512, 1) void k_scan_mfma(
    const bf16* __restrict__ xwp,   // permuted [SEQ*4][512 tid][16]
    const bf16* __restrict__ wt,    // [HIDDEN n][HIDDEN k]
    const float* __restrict__ h0,   // [BATCH][HIDDEN]
    bf16* __restrict__ hh,          // [BATCH][SEQ][HIDDEN]
    float* __restrict__ hfin)       // [BATCH][HIDDEN]
{
    __shared__ bf16 hp[2][16 * CSTR];        // 2 x 18.25 KB

    const int tid  = threadIdx.x;
    const int lane = tid & 63, wid = tid >> 6;    // 8 waves
    const int b0   = blockIdx.x * ROWS;
    const int scol = wid * 64;                    // wave's 64-col slice
    const int lm   = lane & 15, lk = lane >> 4;

    // row-major slice (row=tid>>5, cols cbase..cbase+15) <-> fragment addr
    const int row   = tid >> 5, cbase = (tid & 31) * 16;
    const int raddr = (cbase >> 5) * CSTR +
                      (((cbase & 31) >> 3) * 2 + (row >> 3)) * GSTR + (row & 7) * 8;
    // af read offset: block = lane (identity, conflict-free)
    const int gofs  = (lane >> 3) * GSTR + (lane & 7) * 8;

    // ---- one-time: h0 -> hp[0] ----
    {
        const float* src = h0 + (size_t)(b0 + row) * HIDDEN + cbase;
        bf16 tmp[16];
#pragma unroll
        for (int j = 0; j < 16; ++j) tmp[j] = __float2bfloat16(src[j]);
        *reinterpret_cast<uint4*>(&hp[0][raddr])            = *reinterpret_cast<uint4*>(&tmp[0]);
        *reinterpret_cast<uint4*>(&hp[0][raddr + 2 * GSTR]) = *reinterpret_cast<uint4*>(&tmp[8]);
    }

    // ---- one-time: ALL W fragments -> registers (256/wave), pinned vs remat ----
    bf16x8 breg[16][4];
#pragma unroll
    for (int c = 0; c < 16; ++c)
#pragma unroll
        for (int nt = 0; nt < 4; ++nt) {
            breg[c][nt] = *reinterpret_cast<const bf16x8*>(
                wt + (size_t)(scol + nt * 16 + lm) * HIDDEN + c * 32 + lk * 8);
            asm volatile("" : "+v"(breg[c][nt]));   // opaque: no remat
        }

    __syncthreads();

    int p = 0;
    for (int t = 0; t < SEQ; ++t) {
        // store h(t-1) -> hh (2 x b128 LDS read, conflict-free; coalesced 32B global)
        if (t > 0) {
            uint4 v0 = *reinterpret_cast<const uint4*>(&hp[p][raddr]);
            uint4 v1 = *reinterpret_cast<const uint4*>(&hp[p][raddr + 2 * GSTR]);
            bf16* dst = hh + ((size_t)(b0 + row) * SEQ + (t - 1)) * HIDDEN + cbase;
            *reinterpret_cast<uint4*>(dst)     = v0;
            *reinterpret_cast<uint4*>(dst + 8) = v1;
        }

        // xw for this step: 2 uint4 (16 bf16) per thread
        ushort xe[16];
        {
            const uint4* xp = reinterpret_cast<const uint4*>(xwp) +
                              ((size_t)(t * 4 + blockIdx.x) * 512 + tid) * 2;
            *reinterpret_cast<uint4*>(&xe[0]) = xp[0];
            *reinterpret_cast<uint4*>(&xe[8]) = xp[1];
        }

        f32x4 acc[4] = {};
#pragma unroll
        for (int kc = 0; kc < 16; ++kc) {
            bf16x8 af = *reinterpret_cast<const bf16x8*>(&hp[p][kc * CSTR + gofs]);
            acc[0] = __builtin_amdgcn_mfma_f32_16x16x32_bf16(af, breg[kc][0], acc[0], 0, 0, 0);
            acc[1] = __builtin_amdgcn_mfma_f32_16x16x32_bf16(af, breg[kc][1], acc[1], 0, 0, 0);
            acc[2] = __builtin_amdgcn_mfma_f32_16x16x32_bf16(af, breg[kc][2], acc[2], 0, 0, 0);
            acc[3] = __builtin_amdgcn_mfma_f32_16x16x32_bf16(af, breg[kc][3], acc[3], 0, 0, 0);
        }

        // epilogue: h_new -> hp[p^1] fragment order (32 distinct banks per write op)
        {
            bf16* hw = &hp[p ^ 1][0];
#pragma unroll
            for (int nt = 0; nt < 4; ++nt)
#pragma unroll
                for (int r = 0; r < 4; ++r) {
                    float pre = acc[nt][r] + bfu(xe[nt * 4 + r]);
                    float e2  = __expf(2.f * pre);
                    float rc  = __builtin_amdgcn_rcpf(e2 + 1.f);
                    float hn  = fmaf(-2.f, rc, 1.f);        // tanh(pre)
                    int m   = lk * 4 + r;
                    int blk = (((nt & 1) * 16 + lm) >> 3) * 16 + m;
                    hw[(wid * 2 + (nt >> 1)) * CSTR +
                       (blk >> 3) * GSTR + (blk & 7) * 8 + (lm & 7)] = __float2bfloat16(hn);
                }
        }
        p ^= 1;
        __syncthreads();    // single barrier per step
    }

    // final: h(SEQ-1) -> hh and hfin
    {
        uint4 v0 = *reinterpret_cast<const uint4*>(&hp[p][raddr]);
        uint4 v1 = *reinterpret_cast<const uint4*>(&hp[p][raddr + 2 * GSTR]);
        bf16* dst = hh + ((size_t)(b0 + row) * SEQ + (SEQ - 1)) * HIDDEN + cbase;
        *reinterpret_cast<uint4*>(dst)     = v0;
        *reinterpret_cast<uint4*>(dst + 8) = v1;
        const ushort* u0 = reinterpret_cast<const ushort*>(&v0);
        const ushort* u1 = reinterpret_cast<const ushort*>(&v1);
        float* fdst = hfin + (size_t)(b0 + row) * HIDDEN + cbase;
#pragma unroll
        for (int j = 0; j < 8; ++j) { fdst[j] = bfu(u0[j]); fdst[j + 8] = bfu(u1[j]); }
    }
}

// ---------------- launch ----------------
extern "C" void kernel_launch(void* const* d_in, const int* in_sizes, int n_in,
                              void* d_out, int out_size, void* d_ws, size_t ws_size,
                              hipStream_t stream) {
    const int*   x    = (const int*)  d_in[0];
    const float* h0   = (const float*)d_in[1];
    const float* emb  = (const float*)d_in[2];
    const float* wxh  = (const float*)d_in[3];
    const float* whh  = (const float*)d_in[4];
    const float* bh   = (const float*)d_in[5];
    const float* whyw = (const float*)d_in[6];
    const float* whyb = (const float*)d_in[7];

    float* logits = (float*)d_out;                            // [BATCH][SEQ][VOCAB]
    float* hfin   = logits + (size_t)BATCH * SEQ * VOCAB;     // [BATCH][HIDDEN]

    char* p = (char*)d_ws;
    bf16* xwp    = (bf16*)p; p += (size_t)SEQ * BATCH * HIDDEN * 2;
    bf16* hh     = (bf16*)p; p += (size_t)BATCH * SEQ * HIDDEN * 2;
    bf16* wt     = (bf16*)p; p += (size_t)HIDDEN * HIDDEN * 2;
    bf16* wxh_t  = (bf16*)p; p += (size_t)HIDDEN * EMBED * 2;
    bf16* emb_bf = (bf16*)p; p += (size_t)VOCAB * EMBED * 2;
    bf16* why_bf = (bf16*)p; p += (size_t)VOCAB * HIDDEN * 2;

    k_txp_whh<<<(HIDDEN * HIDDEN + 255) / 256, 256, 0, stream>>>(whh, wt);
    k_cvt<<<(VOCAB * EMBED + 255) / 256, 256, 0, stream>>>(emb, emb_bf, VOCAB * EMBED);
    k_cvt<<<(VOCAB * HIDDEN + 255) / 256, 256, 0, stream>>>(whyw, why_bf, VOCAB * HIDDEN);
    k_txp_wxh<<<(EMBED * HIDDEN + 255) / 256, 256, 0, stream>>>(wxh, wxh_t);

    // phase 1: xwp = permute(emb[x] @ W_xh + b_h)
    k_gemm<true, true, true><<<dim3((SEQ * BATCH) / 64, HIDDEN / 64), 256, 0, stream>>>(
        emb_bf, x, wxh_t, bh, nullptr, xwp, SEQ * BATCH, HIDDEN, EMBED);

    // phase 2: the recurrence (4 blocks x 16 batch rows, 512 threads / 8 waves)
    k_scan_mfma<<<BATCH / ROWS, 512, 0, stream>>>(xwp, wt, h0, hh, hfin);

    // phase 3: logits = hh @ W_hy^T + b
    k_gemm<false, false, false><<<dim3((BATCH * SEQ) / 64, VOCAB / 64), 256, 0, stream>>>(
        hh, nullptr, why_bf, whyb, logits, nullptr, BATCH * SEQ, VOCAB, HIDDEN);
}